// Round 3
// baseline (996.435 us; speedup 1.0000x reference)
//
#include <hip/hip_runtime.h>
#include <stdint.h>

// Problem constants
#define BATCH 2
#define CIN 128
#define COUT 512
#define DD 8
#define PSPAT 8192          // D*H*W
#define NA 9                // anchors per position
#define NANCH 73728         // PSPAT*NA
#define PRE 2048
#define POST 300
#define CAP 4096            // candidate buffer (top-2048 + cutoff-bin ties)
#define NMS_TH 0.7f

typedef unsigned short u16;
typedef _Float16 f16x8 __attribute__((ext_vector_type(8)));
typedef float f32x16 __attribute__((ext_vector_type(16)));
typedef unsigned int uint32x4 __attribute__((ext_vector_type(4)));

// ws layout (byte offsets) — EXACTLY the proven 46,104,576-B footprint.
// Selection scratch aliases Wg (dead only after k_conv; hist zeroed after
// k_conv — R10 lesson).
// R15: k_conv restructured — acts feed MFMA B-frags DIRECTLY from global
// (reg-split, no LDS round-trip); weights double-buffered in LDS (2x32KB),
// ONE barrier per stage, WISSUE at stage top (T3-lite 2-phase). W rows are
// 256B (hi|lo interleaved) with 4-bit XOR pre-swizzle -> min-throughput
// ds_read_b128. R14 was latency/barrier-bound (Mfma 16%, VALU 17%, 2 drains
// per stage, 192KB LDS/block-stage).
constexpr size_t OFF_WT   = 0;          // 108*2 blocks * 32KB = 7,077,888 B (f16 hi/lo image)
constexpr size_t OFF_WHT  = 7077888;    // 512*80 f32       = 163,840 B
constexpr size_t OFF_X    = 7241728;    // 2*512*8192 f32   = 33,554,432 B
constexpr size_t OFF_SC   = 40796160;   // 2*73728 f32      = 589,824 B
constexpr size_t OFF_BX   = 41385984;   // 2*73728*6 f32    = 3,538,944 B
constexpr size_t OFF_SB   = 44957696;   // 2*2048*6 f32     = 98,304 B
constexpr size_t OFF_MK   = 45056000;   // 2*2048*32 u64    = 1,048,576 B  (end 46,104,576)
// selection scratch inside [0, OFF_WT+7MB), used only after k_conv:
constexpr size_t OFF_HIST = 16;              // 2*65536 u32 = 524,288 B
constexpr size_t OFF_CAND = 524304;          // 2*4096 u64  = 65,536 B

// ---------------- fused weight transforms (one launch) ----------------
// Wg: per (nt,tap,cihalf): 32 KB block = 128 rows (local cout) x 256 B.
// Row n holds 64 hi f16 (bytes 0..127 logical) then 64 lo f16, as 16 columns
// of 16 B, stored column = logical ^ (n&15)  (4-bit XOR swizzle; bijective).
// This is the EXACT LDS image k_conv wants, so global_load_lds copies it
// linearly (pre-swizzled-source, m173), and ds_read_b128 frag reads are
// minimum-throughput (8 lanes per 4-bank group over the wave).
// f16 split with x1024 scale: wh+wl = 1024*w, residual floor ~2^-22 rel.
#define NT_WT   (27 * 128 * 512)
#define NT_WHT  (512 * 80)
__global__ void k_wtrans(const float* __restrict__ Wc, u16* __restrict__ Wg,
                         const float* __restrict__ Wcls, const float* __restrict__ Wbb,
                         float* __restrict__ Wht) {
    int e = blockIdx.x * blockDim.x + threadIdx.x;
    if (e < NT_WT) {
        const int k    = e & 63;
        const int n    = (e >> 6) & 127;
        const int half = (e >> 13) & 1;
        const int rest = e >> 14;            // nt*27 + tap, [0,108)
        const int co = (rest / 27) * 128 + n;
        const int ci = half * 64 + k;
        const int tp = rest % 27;
        const float v = Wc[(co * 128 + ci) * 27 + tp] * 1024.f;
        const _Float16 h = (_Float16)v;
        const _Float16 l = (_Float16)(v - (float)h);
        char* rb = (char*)Wg + (((size_t)(rest * 2 + half)) << 15) + n * 256;
        const int hcol = (k >> 3) ^ (n & 15);
        const int lcol = ((k >> 3) | 8) ^ (n & 15);
        const int kb = (k & 7) << 1;
        *(u16*)(rb + (hcol << 4) + kb) = __builtin_bit_cast(unsigned short, h);
        *(u16*)(rb + (lcol << 4) + kb) = __builtin_bit_cast(unsigned short, l);
        return;
    }
    e -= NT_WT;
    if (e >= NT_WHT) return;
    int q = e % 80;
    int c = e / 80;
    int og = q / 10, k = q % 10;
    int o = og * 9 + k;
    float v = 0.f;
    if (k < 9) v = (o < 18) ? Wcls[o * 512 + c] : Wbb[(o - 18) * 512 + c];
    Wht[e] = v;
}

// ---------------- conv3d 3x3x3 + bias + relu: MFMA implicit GEMM ----------------
// M=cout(128-tile), N=spatial(128 pts: fixed d, 4 h-rows), K=tap*ci.
// f16 2-way split (x1024), 3 products into ONE fp32 accumulator:
//   acc += Wh*Xh + Wh*Xl + Wl*Xh   (numerically IDENTICAL to R14's passing
//   kernel: same split, same scale, same accumulation order).
// Acts: B-frags built in registers straight from global f32 (lane=(pt,koct)
// needs 8 ci-contiguous values -> 8 dword loads, 2x128B segments each; no
// LDS for acts at all). Weights: double-buffered 2x32KB LDS via
// global_load_lds from pre-swizzled Wg; ONE barrier per stage, prefetch
// issued at stage top so the barrier vmcnt-drain lands after compute.
#define MFMA(A, B, C) __builtin_amdgcn_mfma_f32_32x32x16_f16((A), (B), (C), 0, 0, 0)
#define Z16 {0.f,0.f,0.f,0.f,0.f,0.f,0.f,0.f,0.f,0.f,0.f,0.f,0.f,0.f,0.f,0.f}

#define PK2(YA, YB, UH, UL) { \
    const float sa_ = (YA) * 1024.f, sb_ = (YB) * 1024.f; \
    const _Float16 ha_ = (_Float16)sa_, hb_ = (_Float16)sb_; \
    const _Float16 la_ = (_Float16)(sa_ - (float)ha_); \
    const _Float16 lb_ = (_Float16)(sb_ - (float)hb_); \
    UH = (unsigned)__builtin_bit_cast(unsigned short, ha_) | \
         ((unsigned)__builtin_bit_cast(unsigned short, hb_) << 16); \
    UL = (unsigned)__builtin_bit_cast(unsigned short, la_) | \
         ((unsigned)__builtin_bit_cast(unsigned short, lb_) << 16); }

// Build one B-frag (N=frag row-group, KK=k16 chunk): 8 f32 loads + split/pack.
#define BLD(N, KK, BH, BL) { \
    const int h2_ = hb_ + (N); \
    const bool ok_ = okw_ && ((unsigned)h2_ < 32u); \
    const float* ap_ = in + (((size_t)(cb0_ + ((KK) << 4))) << 13) + spo_ + (h2_ << 5); \
    const float y0_ = ok_ ? ap_[0]     : 0.f; \
    const float y1_ = ok_ ? ap_[8192]  : 0.f; \
    const float y2_ = ok_ ? ap_[16384] : 0.f; \
    const float y3_ = ok_ ? ap_[24576] : 0.f; \
    const float y4_ = ok_ ? ap_[32768] : 0.f; \
    const float y5_ = ok_ ? ap_[40960] : 0.f; \
    const float y6_ = ok_ ? ap_[49152] : 0.f; \
    const float y7_ = ok_ ? ap_[57344] : 0.f; \
    unsigned uh0_, uh1_, uh2_, uh3_, ul0_, ul1_, ul2_, ul3_; \
    PK2(y0_, y1_, uh0_, ul0_) PK2(y2_, y3_, uh1_, ul1_) \
    PK2(y4_, y5_, uh2_, ul2_) PK2(y6_, y7_, uh3_, ul3_) \
    { uint32x4 th_ = {uh0_, uh1_, uh2_, uh3_}; BH = __builtin_bit_cast(f16x8, th_); } \
    { uint32x4 tl_ = {ul0_, ul1_, ul2_, ul3_}; BL = __builtin_bit_cast(f16x8, tl_); } }

// All 16 B-frags for stage S (2 N-frags x 4 k16-chunks, hi+lo).
#define ALOADCVT(S) { \
    const int tap_ = t0 + ((S) >> 1); \
    const int kd_ = tap_ / 9, kh_ = (tap_ / 3) % 3, kw_ = tap_ % 3; \
    const int id_ = d0 + kd_ - 1; \
    const int w2_ = l31 + kw_ - 1; \
    const bool okw_ = (unsigned)w2_ < 32u; \
    const int hb_ = h0 + (wn << 1) + kh_ - 1; \
    const int cb0_ = b * CIN + (((S) & 1) << 6) + (cq << 3); \
    const long long spo_ = ((long long)id_ << 10) + w2_; \
    BLD(0, 0, bh00, bl00) BLD(0, 1, bh01, bl01) BLD(0, 2, bh02, bl02) BLD(0, 3, bh03, bl03) \
    BLD(1, 0, bh10, bl10) BLD(1, 1, bh11, bl11) BLD(1, 2, bh12, bl12) BLD(1, 3, bh13, bl13) }

// Stage S weights (32 KB) -> LDS buffer BUF via global_load_lds, linear copy.
#define WISSUE(S, BUF) { \
    const int tap_ = t0 + ((S) >> 1); \
    const char* gw_ = WgB + (((size_t)((nt * 27 + tap_) * 2 + ((S) & 1))) << 15) \
                    + (wv << 13) + ln16; \
    char* lb_ = smem + ((BUF) << 15) + (wv << 13); \
    _Pragma("unroll") \
    for (int j_ = 0; j_ < 8; ++j_) \
        __builtin_amdgcn_global_load_lds( \
            (const __attribute__((address_space(1))) void*)(gw_ + (j_ << 10)), \
            (__attribute__((address_space(3))) void*)(lb_ + (j_ << 10)), 16, 0, 0); }

#define KKSTEP(KK, BH0, BL0, BH1, BL1) { \
    const int ch_ = ((((KK) << 1) + cq) ^ rsw) << 4; \
    const int cl_ = (((((KK) << 1) + cq) | 8) ^ rsw) << 4; \
    const char* r0_ = wb_ + (rm0 << 8); \
    const char* r1_ = wb_ + (rm1 << 8); \
    const f16x8 wh0 = *(const f16x8*)(r0_ + ch_); \
    const f16x8 wl0 = *(const f16x8*)(r0_ + cl_); \
    const f16x8 wh1 = *(const f16x8*)(r1_ + ch_); \
    const f16x8 wl1 = *(const f16x8*)(r1_ + cl_); \
    acc00 = MFMA(wh0, BH0, acc00); acc00 = MFMA(wh0, BL0, acc00); acc00 = MFMA(wl0, BH0, acc00); \
    acc01 = MFMA(wh0, BH1, acc01); acc01 = MFMA(wh0, BL1, acc01); acc01 = MFMA(wl0, BH1, acc01); \
    acc10 = MFMA(wh1, BH0, acc10); acc10 = MFMA(wh1, BL0, acc10); acc10 = MFMA(wl1, BH0, acc10); \
    acc11 = MFMA(wh1, BH1, acc11); acc11 = MFMA(wh1, BL1, acc11); acc11 = MFMA(wl1, BH1, acc11); }

#define COMPUTE(BUF) { \
    const char* wb_ = smem + ((BUF) << 15); \
    KKSTEP(0, bh00, bl00, bh10, bl10) \
    KKSTEP(1, bh01, bl01, bh11, bl11) \
    KKSTEP(2, bh02, bl02, bh12, bl12) \
    KKSTEP(3, bh03, bl03, bh13, bl13) }

// acc = 2^20 * conv -> unscale exactly, + bias, relu
#define EPI(ACC, MI, NI) { \
    const int coB_ = co0 + (wm << 6) + ((MI) << 5) + hl4; \
    const int pt_  = p0 + (wn << 6) + ((NI) << 5) + l31; \
    _Pragma("unroll") \
    for (int g_ = 0; g_ < 4; ++g_) { \
        _Pragma("unroll") \
        for (int q_ = 0; q_ < 4; ++q_) { \
            const int co_ = coB_ + (g_ << 3) + q_; \
            const float v_ = ACC[g_ * 4 + q_] * 9.5367431640625e-07f + bconv[co_]; \
            x[((size_t)((b << 9) + co_) << 13) + pt_] = fmaxf(v_, 0.f); \
        } } }

__global__ __launch_bounds__(256, 2) void k_conv(const float* __restrict__ in,
                                                 const u16* __restrict__ Wg,
                                                 const float* __restrict__ bconv,
                                                 float* __restrict__ x) {
    __shared__ __align__(16) char smem[65536];   // W double-buffer: 2 x 32 KB
    const int tid  = threadIdx.x;
    const int bx   = blockIdx.x;        // 64 spatial tiles (128 pts each)
    const int nt   = blockIdx.y;        // 4 cout tiles of 128
    const int b    = blockIdx.z;
    const int p0   = bx << 7;
    const int d0   = bx >> 3;
    const int h0   = (bx & 7) << 2;
    const int co0  = nt << 7;

    const int lane = tid & 63;
    const int wv   = tid >> 6;          // wave id
    const int wm   = wv & 1;            // cout 64-half
    const int wn   = wv >> 1;           // pt 64-half
    const int l31  = lane & 31;         // frag row/col
    const int cq   = lane >> 5;         // frag k-octet half
    const int hl4  = cq << 2;           // C/D row group
    const int rsw  = l31 & 15;          // W-row XOR swizzle key
    const int rm0  = (wm << 6) + l31;   // weight LDS rows (256 B each)
    const int rm1  = rm0 + 32;
    const int ln16 = lane << 4;

    const int t0   = (d0 == 0) ? 9 : 0;
    const int nTap = 27 - (((d0 == 0) || (d0 == 7)) ? 9 : 0);
    const int NS   = nTap * 2;          // stages: tap x 2 ci-halves of 64

    const char* WgB = (const char*)Wg;

    f16x8 bh00, bh01, bh02, bh03, bh10, bh11, bh12, bh13;
    f16x8 bl00, bl01, bl02, bl03, bl10, bl11, bl12, bl13;
    f32x16 acc00 = Z16, acc01 = Z16, acc10 = Z16, acc11 = Z16;

    WISSUE(0, 0)
    __syncthreads();                    // drain prologue W staging

    for (int s = 0; s < NS; ++s) {
        if (s + 1 < NS) { WISSUE(s + 1, (s + 1) & 1) }   // async into alt buf
        ALOADCVT(s)                     // acts -> reg frags (64 loads + cvt)
        COMPUTE(s & 1)                  // 16 ds_read_b128 + 48 MFMA
        __syncthreads();                // drains alt staging; guards cur reuse
    }

    EPI(acc00, 0, 0)
    EPI(acc01, 0, 1)
    EPI(acc10, 1, 0)
    EPI(acc11, 1, 1)
}

// ---------------- heads GEMM + score/box epilogue + fused score histogram ----------------
// R12 form (measured best): unchanged.
__global__ __launch_bounds__(256) void k_heads(const float* __restrict__ x,
                                               const float* __restrict__ Wht,
                                               const float* __restrict__ bcls,
                                               const float* __restrict__ bbb,
                                               const float* __restrict__ iminfo,
                                               float* __restrict__ scores,
                                               float* __restrict__ boxes,
                                               unsigned int* __restrict__ hist) {
    __shared__ __align__(16) float smx[4096];    // x chunk [ch32][pt128]  16 KB
    __shared__ __align__(16) float Whs[2560];    // weight chunk [kk32][80] 10 KB
    __shared__ __align__(16) float ex[10240];    // exchange [pt128][80]    40 KB
    const int tid = threadIdx.x;
    const int p0  = blockIdx.x * 128;
    const int b   = blockIdx.y;
    const int pl  = tid & 31;     // 32 point-lanes, 4 consecutive points each
    const int og  = tid >> 5;     // 8 output groups of 9

    float acc[4][9] = {};

    for (int cc = 0; cc < 512; cc += 32) {
        __syncthreads();
        #pragma unroll
        for (int i = 0; i < 4; ++i) {
            int e4 = tid + i * 256;          // 1024 float4s
            int ch = e4 >> 5;
            int pt4 = (e4 & 31) * 4;
            *(float4*)&smx[ch * 128 + pt4] =
                *(const float4*)&x[((size_t)(b * COUT + cc + ch) << 13) + p0 + pt4];
        }
        #pragma unroll
        for (int i = 0; i < 10; ++i) {
            int e = tid + i * 256;
            Whs[e] = Wht[cc * 80 + e];
        }
        __syncthreads();
        for (int kk = 0; kk < 32; ++kk) {
            float4 a4 = *(const float4*)&smx[kk * 128 + pl * 4];
            const float* wp = &Whs[kk * 80 + og * 10];
            float2 w0 = *(const float2*)(wp);
            float2 w1 = *(const float2*)(wp + 2);
            float2 w2 = *(const float2*)(wp + 4);
            float2 w3 = *(const float2*)(wp + 6);
            float  w8 = wp[8];
            float wv[9] = {w0.x, w0.y, w1.x, w1.y, w2.x, w2.y, w3.x, w3.y, w8};
            #pragma unroll
            for (int k = 0; k < 9; ++k) {
                float wk = wv[k];
                acc[0][k] += a4.x * wk;
                acc[1][k] += a4.y * wk;
                acc[2][k] += a4.z * wk;
                acc[3][k] += a4.w * wk;
            }
        }
    }

    __syncthreads();
    #pragma unroll
    for (int pi = 0; pi < 4; ++pi)
        #pragma unroll
        for (int k = 0; k < 9; ++k)
            ex[(pl * 4 + pi) * 80 + og * 10 + k] = acc[pi][k];
    __syncthreads();

    if (tid < 128) {
        const int p = p0 + tid;
        float v[72];
        #pragma unroll
        for (int og2 = 0; og2 < 8; ++og2)
            #pragma unroll
            for (int k = 0; k < 9; ++k)
                v[og2 * 9 + k] = ex[tid * 80 + og2 * 10 + k];

        const float im0 = iminfo[b * 3 + 0], im1 = iminfo[b * 3 + 1], im2 = iminfo[b * 3 + 2];
        const float hix = im2 - 1.f, hiy = im1 - 1.f, hiz = im0 - 1.f;
        const int d = p >> 10, h = (p >> 5) & 31, w = p & 31;
        const float sx = w * 8.f, sy = h * 8.f, sz = d * 8.f;

        #pragma unroll 1
        for (int a = 0; a < 9; ++a) {
            float c0 = v[a] + bcls[a];
            float c1 = v[9 + a] + bcls[9 + a];
            float m  = fmaxf(c0, c1);
            float e0 = expf(c0 - m), e1 = expf(c1 - m);
            float sc = e1 / (e0 + e1);
            scores[b * NANCH + p * 9 + a] = sc;
            atomicAdd(&hist[b * 65536 + (__float_as_uint(sc) >> 16)], 1u);

            float aw = (float)(32 << (a % 3));                 // x,y size = 8*SCALES
            float ad = aw * 0.5f * (float)(1 << (a / 3));      // z size = aw*RATIOS
            float ax1 = sx + 3.5f - 0.5f * (aw - 1.f);
            float ax2 = sx + 3.5f + 0.5f * (aw - 1.f);
            float ay1 = sy + 3.5f - 0.5f * (aw - 1.f);
            float ay2 = sy + 3.5f + 0.5f * (aw - 1.f);
            float az1 = sz + 3.5f - 0.5f * (ad - 1.f);
            float az2 = sz + 3.5f + 0.5f * (ad - 1.f);
            float ww_ = ax2 - ax1 + 1.f, hh_ = ay2 - ay1 + 1.f, dd_ = az2 - az1 + 1.f;
            float cx = ax1 + 0.5f * ww_, cy = ay1 + 0.5f * hh_, cz = az1 + 0.5f * dd_;

            const float* dv = &v[18 + a * 6];
            float dx = dv[0] + bbb[a * 6 + 0];
            float dy = dv[1] + bbb[a * 6 + 1];
            float dz = dv[2] + bbb[a * 6 + 2];
            float dw = dv[3] + bbb[a * 6 + 3];
            float dh = dv[4] + bbb[a * 6 + 4];
            float dd2 = dv[5] + bbb[a * 6 + 5];
            float pcx = dx * ww_ + cx, pcy = dy * hh_ + cy, pcz = dz * dd_ + cz;
            float pw = expf(dw) * ww_, ph = expf(dh) * hh_, pd = expf(dd2) * dd_;
            float x1 = fminf(fmaxf(pcx - 0.5f * pw, 0.f), hix);
            float y1 = fminf(fmaxf(pcy - 0.5f * ph, 0.f), hiy);
            float z1 = fminf(fmaxf(pcz - 0.5f * pd, 0.f), hiz);
            float x2 = fminf(fmaxf(pcx + 0.5f * pw, 0.f), hix);
            float y2 = fminf(fmaxf(pcy + 0.5f * ph, 0.f), hiy);
            float z2 = fminf(fmaxf(pcz + 0.5f * pd, 0.f), hiz);
            float* bp = &boxes[(size_t)(b * NANCH + p * 9 + a) * 6];
            bp[0] = x1; bp[1] = y1; bp[2] = z1; bp[3] = x2; bp[4] = y2; bp[5] = z2;
        }
    }
}

// ---------------- fused cutoff + compact (one block per batch) ----------------
__global__ __launch_bounds__(1024) void k_cutcompact(const float* __restrict__ scores,
                                                     const unsigned int* __restrict__ hist,
                                                     unsigned long long* __restrict__ cand) {
    __shared__ unsigned int cs[1024], scan[1024];
    __shared__ unsigned int sh_cut, sh_pos;
    const int b = blockIdx.x, tid = threadIdx.x;
    const unsigned int* h = hist + b * 65536;
    unsigned int s = 0;
    for (int i = 0; i < 64; ++i) s += h[tid * 64 + i];
    cs[tid] = s; scan[tid] = s;
    if (tid == 0) sh_pos = 0;
    __syncthreads();
    for (int d = 1; d < 1024; d <<= 1) {           // scan[c] -> sum_{c'>=c} cs[c']
        unsigned int v = scan[tid];
        unsigned int add = (tid + d < 1024) ? scan[tid + d] : 0u;
        __syncthreads();
        scan[tid] = v + add;
        __syncthreads();
    }
    unsigned int above = (tid + 1 < 1024) ? scan[tid + 1] : 0u;   // strictly above this chunk
    if (above < PRE && above + cs[tid] >= PRE) {   // exactly one thread
        unsigned int cum = above;
        for (int x = tid * 64 + 63; x >= tid * 64; --x) {
            cum += h[x];
            if (cum >= PRE) { sh_cut = (unsigned int)x; break; }
        }
    }
    __syncthreads();
    const unsigned int cut = sh_cut;
    const float* sc = scores + b * NANCH;
    for (int i = tid; i < NANCH; i += 1024) {
        unsigned int u = __float_as_uint(sc[i]);
        if ((u >> 16) >= cut) {
            unsigned int pos = atomicAdd(&sh_pos, 1u);
            if (pos < CAP) cand[b * CAP + pos] = ((unsigned long long)(~u) << 32) | (unsigned)i;
        }
    }
    __syncthreads();
    const unsigned int cnt = (sh_pos < CAP) ? sh_pos : CAP;
    for (int i = (int)cnt + tid; i < CAP; i += 1024)
        cand[b * CAP + i] = ~0ull;
}

// bitonic sort CAP keys asc (key = ~score_bits || idx => score desc, idx asc);
// first 2048 are the sorted top-2048; gather their boxes.
__global__ __launch_bounds__(1024) void k_sort2(const unsigned long long* __restrict__ cand,
                                                const float* __restrict__ boxes,
                                                float* __restrict__ sboxes) {
    __shared__ unsigned long long sk[CAP];
    const int b = blockIdx.x, tid = threadIdx.x;
    for (int i = tid; i < CAP; i += 1024) sk[i] = cand[b * CAP + i];
    __syncthreads();
    for (int k = 2; k <= CAP; k <<= 1) {
        for (int j = k >> 1; j > 0; j >>= 1) {
            #pragma unroll 1
            for (int i = tid; i < CAP; i += 1024) {
                int ixj = i ^ j;
                if (ixj > i) {
                    unsigned long long va = sk[i], vb = sk[ixj];
                    bool up = ((i & k) == 0);
                    if ((va > vb) == up) { sk[i] = vb; sk[ixj] = va; }
                }
            }
            __syncthreads();
        }
    }
    for (int r = tid; r < PRE; r += 1024) {
        unsigned int n = (unsigned int)(sk[r] & 0xFFFFFFFFull);
        const float* src = &boxes[(size_t)(b * NANCH + (int)n) * 6];
        float* dst = &sboxes[(size_t)(b * PRE + r) * 6];
        #pragma unroll
        for (int c = 0; c < 6; ++c) dst[c] = src[c];
    }
}

// suppression bitmask (upper triangle only): mask[b][i][w] bit j <=> j>i && IoU>0.7
__global__ __launch_bounds__(256) void k_mask(const float* __restrict__ sboxes,
                                              unsigned long long* __restrict__ mask) {
    if (blockIdx.y < blockIdx.x) return;   // j0 < i0: never read (k_nms gates by word)
    __shared__ float rb[64 * 6], cb[64 * 6];
    const int i0 = blockIdx.x * 64, j0 = blockIdx.y * 64, b = blockIdx.z;
    const int tid = threadIdx.x;
    for (int e = tid; e < 384; e += 256) {
        rb[e] = sboxes[(size_t)(b * PRE + i0) * 6 + e];
        cb[e] = sboxes[(size_t)(b * PRE + j0) * 6 + e];
    }
    __syncthreads();
    const int wave = tid >> 6, lane = tid & 63;
    const float bx1 = cb[lane * 6 + 0], by1 = cb[lane * 6 + 1], bz1 = cb[lane * 6 + 2];
    const float bx2 = cb[lane * 6 + 3], by2 = cb[lane * 6 + 4], bz2 = cb[lane * 6 + 5];
    const float vb = (bx2 - bx1 + 1.f) * (by2 - by1 + 1.f) * (bz2 - bz1 + 1.f);
    const int j = j0 + lane;
    for (int rr = 0; rr < 16; ++rr) {
        const int il = wave * 16 + rr;
        const int i = i0 + il;
        float ax1 = rb[il * 6 + 0], ay1 = rb[il * 6 + 1], az1 = rb[il * 6 + 2];
        float ax2 = rb[il * 6 + 3], ay2 = rb[il * 6 + 4], az2 = rb[il * 6 + 5];
        float va = (ax2 - ax1 + 1.f) * (ay2 - ay1 + 1.f) * (az2 - az1 + 1.f);
        float ix = fmaxf(fminf(ax2, bx2) - fmaxf(ax1, bx1) + 1.f, 0.f);
        float iy = fmaxf(fminf(ay2, by2) - fmaxf(ay1, by1) + 1.f, 0.f);
        float iz = fmaxf(fminf(az2, bz2) - fmaxf(az1, bz1) + 1.f, 0.f);
        float inter = ix * iy * iz;
        float iou = inter / (va + vb - inter);
        bool bit = (j > i) && (iou > NMS_TH);
        unsigned long long word = __ballot(bit);
        if (lane == 0) mask[(size_t)(b * PRE + i) * 32 + (j0 >> 6)] = word;
    }
}

// single-wave greedy NMS scan + ROI output; 8-deep mask-row prefetch.
__global__ __launch_bounds__(64) void k_nms(const unsigned long long* __restrict__ mask,
                                            const float* __restrict__ sboxes,
                                            float* __restrict__ out) {
    const int b = blockIdx.x, lane = threadIdx.x;
    __shared__ int sel[POST];
    unsigned long long keep = ~0ull;          // lane l<32 owns bits [64l,64l+64)
    const int lw = lane & 31;
    const unsigned long long* mrow = mask + (size_t)b * PRE * 32 + lw;
    unsigned long long b0 = mrow[0 * 32], b1 = mrow[1 * 32], b2 = mrow[2 * 32], b3 = mrow[3 * 32];
    unsigned long long b4 = mrow[4 * 32], b5 = mrow[5 * 32], b6 = mrow[6 * 32], b7 = mrow[7 * 32];
    int kcount = 0;

#define NMS_STEP(J, BUF)                                                        \
    {                                                                           \
        int i = i0 + (J);                                                       \
        unsigned long long cur = (lw >= (i >> 6)) ? BUF : 0ull;                 \
        int nr = i0 + 8 + (J);                                                  \
        BUF = (nr < PRE) ? mrow[(size_t)nr * 32] : 0ull;                        \
        unsigned long long kw = __shfl(keep, i >> 6);                           \
        if ((kw >> (i & 63)) & 1ull) {                                          \
            if (lane < 32) keep &= ~cur;                                        \
            if (lane == 0 && kcount < POST) sel[kcount] = i;                    \
            ++kcount;                                                           \
            if (kcount >= POST) goto nms_done;                                  \
        }                                                                       \
    }

    for (int i0 = 0; i0 < PRE; i0 += 8) {
        NMS_STEP(0, b0) NMS_STEP(1, b1) NMS_STEP(2, b2) NMS_STEP(3, b3)
        NMS_STEP(4, b4) NMS_STEP(5, b5) NMS_STEP(6, b6) NMS_STEP(7, b7)
    }
nms_done:
    __syncthreads();
    const int kc = kcount;
    for (int r = lane; r < POST; r += 64) {
        float* op = &out[(size_t)(b * POST + r) * 7];
        op[0] = (float)b;
        if (r < kc) {
            const float* sb = &sboxes[(size_t)(b * PRE + sel[r]) * 6];
            #pragma unroll
            for (int c = 0; c < 6; ++c) op[1 + c] = sb[c];
        } else {
            #pragma unroll
            for (int c = 0; c < 6; ++c) op[1 + c] = 0.f;
        }
    }
#undef NMS_STEP
}

extern "C" void kernel_launch(void* const* d_in, const int* in_sizes, int n_in,
                              void* d_out, int out_size, void* d_ws, size_t ws_size,
                              hipStream_t stream) {
    const float* base_feat = (const float*)d_in[0];
    const float* im_info   = (const float*)d_in[1];
    const float* W_conv    = (const float*)d_in[4];
    const float* b_conv    = (const float*)d_in[5];
    const float* W_cls     = (const float*)d_in[6];
    const float* b_cls     = (const float*)d_in[7];
    const float* W_bbox    = (const float*)d_in[8];
    const float* b_bbox    = (const float*)d_in[9];

    char* ws = (char*)d_ws;
    u16* Wg        = (u16*)(ws + OFF_WT);
    float* Wht     = (float*)(ws + OFF_WHT);
    float* x       = (float*)(ws + OFF_X);
    float* scores  = (float*)(ws + OFF_SC);
    float* boxes   = (float*)(ws + OFF_BX);
    float* sboxes  = (float*)(ws + OFF_SB);
    unsigned long long* mask = (unsigned long long*)(ws + OFF_MK);
    unsigned int* hist = (unsigned int*)(ws + OFF_HIST);
    unsigned long long* cand = (unsigned long long*)(ws + OFF_CAND);

    const int NTRANS = NT_WT + NT_WHT;
    k_wtrans<<<(NTRANS + 255) / 256, 256, 0, stream>>>(W_conv, Wg, W_cls, W_bbox, Wht);
    k_conv<<<dim3(64, 4, 2), 256, 0, stream>>>(base_feat, Wg, b_conv, x);
    // Wg region dead now; zero hist (aliases Wg) AFTER k_conv, before k_heads.
    hipMemsetAsync(hist, 0, BATCH * 65536 * sizeof(unsigned int), stream);
    k_heads<<<dim3(64, 2), 256, 0, stream>>>(x, Wht, b_cls, b_bbox, im_info, scores, boxes, hist);
    k_cutcompact<<<BATCH, 1024, 0, stream>>>(scores, hist, cand);
    k_sort2<<<BATCH, 1024, 0, stream>>>(cand, boxes, sboxes);
    k_mask<<<dim3(32, 32, 2), 256, 0, stream>>>(sboxes, mask);
    k_nms<<<BATCH, 64, 0, stream>>>(mask, sboxes, (float*)d_out);
}

// Round 4
// 650.727 us; speedup vs baseline: 1.5313x; 1.5313x over previous
//
#include <hip/hip_runtime.h>
#include <stdint.h>

// Problem constants
#define BATCH 2
#define CIN 128
#define COUT 512
#define DD 8
#define PSPAT 8192          // D*H*W
#define NA 9                // anchors per position
#define NANCH 73728         // PSPAT*NA
#define PRE 2048
#define POST 300
#define CAP 4096            // candidate buffer (top-2048 + cutoff-bin ties)
#define NMS_TH 0.7f

typedef unsigned short u16;
typedef _Float16 f16x8 __attribute__((ext_vector_type(8)));
typedef float f32x16 __attribute__((ext_vector_type(16)));
typedef unsigned int uint32x4 __attribute__((ext_vector_type(4)));

// ws layout (byte offsets) — EXACTLY the proven 46,104,576-B footprint.
// Selection scratch aliases Wg (dead only after k_conv; hist zeroed after
// k_conv — R10 lesson).
// R16: R15 + act loads software-pipelined ONE FULL STAGE ahead in registers
// (issue-early/consume-late, G15/T14). R15 was load-latency-bound: MfmaUtil
// 9.9% == 70us-of-MFMA/660us exactly; the per-stage 64 global loads were a
// SYNCHRONOUS chain (load->vmcnt->cvt->MFMA) at 8 waves/CU with L3-latency
// acts (input 16MB > 4MB/XCD L2). Now: cvt(s) from regs loaded at s-1, issue
// loads(s+1), COMPUTE(s) covers their latency; barrier vmcnt-drain lands
// after ~600cyc of cvt+MFMA. sched_barrier(0) pins CVT|ALOAD|COMPUTE order.
constexpr size_t OFF_WT   = 0;          // 108*2 blocks * 32KB = 7,077,888 B (f16 hi/lo image)
constexpr size_t OFF_WHT  = 7077888;    // 512*80 f32       = 163,840 B
constexpr size_t OFF_X    = 7241728;    // 2*512*8192 f32   = 33,554,432 B
constexpr size_t OFF_SC   = 40796160;   // 2*73728 f32      = 589,824 B
constexpr size_t OFF_BX   = 41385984;   // 2*73728*6 f32    = 3,538,944 B
constexpr size_t OFF_SB   = 44957696;   // 2*2048*6 f32     = 98,304 B
constexpr size_t OFF_MK   = 45056000;   // 2*2048*32 u64    = 1,048,576 B  (end 46,104,576)
// selection scratch inside [0, OFF_WT+7MB), used only after k_conv:
constexpr size_t OFF_HIST = 16;              // 2*65536 u32 = 524,288 B
constexpr size_t OFF_CAND = 524304;          // 2*4096 u64  = 65,536 B

// ---------------- fused weight transforms (one launch) ----------------
// Wg: per (nt,tap,cihalf): 32 KB block = 128 rows (local cout) x 256 B.
// Row n holds 64 hi f16 then 64 lo f16, as 16 columns of 16 B, stored
// column = logical ^ (n&15) (4-bit XOR swizzle; bijective). EXACT LDS image
// k_conv wants -> global_load_lds copies linearly (pre-swizzled-source,
// m173); ds_read_b128 frag reads measured 0 bank conflicts (R15).
// f16 split with x1024 scale: wh+wl = 1024*w, residual floor ~2^-22 rel.
#define NT_WT   (27 * 128 * 512)
#define NT_WHT  (512 * 80)
__global__ void k_wtrans(const float* __restrict__ Wc, u16* __restrict__ Wg,
                         const float* __restrict__ Wcls, const float* __restrict__ Wbb,
                         float* __restrict__ Wht) {
    int e = blockIdx.x * blockDim.x + threadIdx.x;
    if (e < NT_WT) {
        const int k    = e & 63;
        const int n    = (e >> 6) & 127;
        const int half = (e >> 13) & 1;
        const int rest = e >> 14;            // nt*27 + tap, [0,108)
        const int co = (rest / 27) * 128 + n;
        const int ci = half * 64 + k;
        const int tp = rest % 27;
        const float v = Wc[(co * 128 + ci) * 27 + tp] * 1024.f;
        const _Float16 h = (_Float16)v;
        const _Float16 l = (_Float16)(v - (float)h);
        char* rb = (char*)Wg + (((size_t)(rest * 2 + half)) << 15) + n * 256;
        const int hcol = (k >> 3) ^ (n & 15);
        const int lcol = ((k >> 3) | 8) ^ (n & 15);
        const int kb = (k & 7) << 1;
        *(u16*)(rb + (hcol << 4) + kb) = __builtin_bit_cast(unsigned short, h);
        *(u16*)(rb + (lcol << 4) + kb) = __builtin_bit_cast(unsigned short, l);
        return;
    }
    e -= NT_WT;
    if (e >= NT_WHT) return;
    int q = e % 80;
    int c = e / 80;
    int og = q / 10, k = q % 10;
    int o = og * 9 + k;
    float v = 0.f;
    if (k < 9) v = (o < 18) ? Wcls[o * 512 + c] : Wbb[(o - 18) * 512 + c];
    Wht[e] = v;
}

// ---------------- conv3d 3x3x3 + bias + relu: MFMA implicit GEMM ----------------
// M=cout(128-tile), N=spatial(128 pts: fixed d, 4 h-rows), K=tap*ci.
// f16 2-way split (x1024), 3 products into ONE fp32 accumulator:
//   acc += Wh*Xh + Wh*Xl + Wl*Xh   (numerically IDENTICAL to R14/R15 passing
//   kernels: same split, same scale, same accumulation order).
// Acts: raw f32 loaded one stage AHEAD into constant-indexed y[2][4][8]
// (SROA->64 VGPRs); cvt to frags at stage top; next-stage loads in flight
// under COMPUTE. Weights: double-buffered 2x32KB LDS via global_load_lds,
// ONE barrier per stage.
#define MFMA(A, B, C) __builtin_amdgcn_mfma_f32_32x32x16_f16((A), (B), (C), 0, 0, 0)
#define Z16 {0.f,0.f,0.f,0.f,0.f,0.f,0.f,0.f,0.f,0.f,0.f,0.f,0.f,0.f,0.f,0.f}

#define PK2(YA, YB, UH, UL) { \
    const float sa_ = (YA) * 1024.f, sb_ = (YB) * 1024.f; \
    const _Float16 ha_ = (_Float16)sa_, hb_ = (_Float16)sb_; \
    const _Float16 la_ = (_Float16)(sa_ - (float)ha_); \
    const _Float16 lb_ = (_Float16)(sb_ - (float)hb_); \
    UH = (unsigned)__builtin_bit_cast(unsigned short, ha_) | \
         ((unsigned)__builtin_bit_cast(unsigned short, hb_) << 16); \
    UL = (unsigned)__builtin_bit_cast(unsigned short, la_) | \
         ((unsigned)__builtin_bit_cast(unsigned short, lb_) << 16); }

// Issue 8 act loads for (N,KK) into persistent y regs (no cvt here).
#define BLDI(N, KK) { \
    const int h2_ = hb_ + (N); \
    const bool ok_ = okw_ && ((unsigned)h2_ < 32u); \
    const float* ap_ = in + (((size_t)(cb0_ + ((KK) << 4))) << 13) + spo_ + (h2_ << 5); \
    y[N][KK][0] = ok_ ? ap_[0]     : 0.f; \
    y[N][KK][1] = ok_ ? ap_[8192]  : 0.f; \
    y[N][KK][2] = ok_ ? ap_[16384] : 0.f; \
    y[N][KK][3] = ok_ ? ap_[24576] : 0.f; \
    y[N][KK][4] = ok_ ? ap_[32768] : 0.f; \
    y[N][KK][5] = ok_ ? ap_[40960] : 0.f; \
    y[N][KK][6] = ok_ ? ap_[49152] : 0.f; \
    y[N][KK][7] = ok_ ? ap_[57344] : 0.f; }

// Issue all 64 act loads for stage S (results consumed at stage S's CVTALL,
// i.e. one iteration later).
#define ALOADISS(S) { \
    const int tap_ = t0 + ((S) >> 1); \
    const int kd_ = tap_ / 9, kh_ = (tap_ / 3) % 3, kw_ = tap_ % 3; \
    const int id_ = d0 + kd_ - 1; \
    const int w2_ = l31 + kw_ - 1; \
    const bool okw_ = (unsigned)w2_ < 32u; \
    const int hb_ = h0 + (wn << 1) + kh_ - 1; \
    const int cb0_ = b * CIN + (((S) & 1) << 6) + (cq << 3); \
    const long long spo_ = ((long long)id_ << 10) + w2_; \
    BLDI(0, 0) BLDI(0, 1) BLDI(0, 2) BLDI(0, 3) \
    BLDI(1, 0) BLDI(1, 1) BLDI(1, 2) BLDI(1, 3) }

#define CVTFRAG(N, KK, BH, BL) { \
    unsigned uh0_, uh1_, uh2_, uh3_, ul0_, ul1_, ul2_, ul3_; \
    PK2(y[N][KK][0], y[N][KK][1], uh0_, ul0_) \
    PK2(y[N][KK][2], y[N][KK][3], uh1_, ul1_) \
    PK2(y[N][KK][4], y[N][KK][5], uh2_, ul2_) \
    PK2(y[N][KK][6], y[N][KK][7], uh3_, ul3_) \
    { uint32x4 th_ = {uh0_, uh1_, uh2_, uh3_}; BH = __builtin_bit_cast(f16x8, th_); } \
    { uint32x4 tl_ = {ul0_, ul1_, ul2_, ul3_}; BL = __builtin_bit_cast(f16x8, tl_); } }

#define CVTALL() { \
    CVTFRAG(0, 0, bh00, bl00) CVTFRAG(0, 1, bh01, bl01) \
    CVTFRAG(0, 2, bh02, bl02) CVTFRAG(0, 3, bh03, bl03) \
    CVTFRAG(1, 0, bh10, bl10) CVTFRAG(1, 1, bh11, bl11) \
    CVTFRAG(1, 2, bh12, bl12) CVTFRAG(1, 3, bh13, bl13) }

// Stage S weights (32 KB) -> LDS buffer BUF via global_load_lds, linear copy.
#define WISSUE(S, BUF) { \
    const int tap_ = t0 + ((S) >> 1); \
    const char* gw_ = WgB + (((size_t)((nt * 27 + tap_) * 2 + ((S) & 1))) << 15) \
                    + (wv << 13) + ln16; \
    char* lb_ = smem + ((BUF) << 15) + (wv << 13); \
    _Pragma("unroll") \
    for (int j_ = 0; j_ < 8; ++j_) \
        __builtin_amdgcn_global_load_lds( \
            (const __attribute__((address_space(1))) void*)(gw_ + (j_ << 10)), \
            (__attribute__((address_space(3))) void*)(lb_ + (j_ << 10)), 16, 0, 0); }

#define KKSTEP(KK, BH0, BL0, BH1, BL1) { \
    const int ch_ = ((((KK) << 1) + cq) ^ rsw) << 4; \
    const int cl_ = (((((KK) << 1) + cq) | 8) ^ rsw) << 4; \
    const char* r0_ = wb_ + (rm0 << 8); \
    const char* r1_ = wb_ + (rm1 << 8); \
    const f16x8 wh0 = *(const f16x8*)(r0_ + ch_); \
    const f16x8 wl0 = *(const f16x8*)(r0_ + cl_); \
    const f16x8 wh1 = *(const f16x8*)(r1_ + ch_); \
    const f16x8 wl1 = *(const f16x8*)(r1_ + cl_); \
    acc00 = MFMA(wh0, BH0, acc00); acc00 = MFMA(wh0, BL0, acc00); acc00 = MFMA(wl0, BH0, acc00); \
    acc01 = MFMA(wh0, BH1, acc01); acc01 = MFMA(wh0, BL1, acc01); acc01 = MFMA(wl0, BH1, acc01); \
    acc10 = MFMA(wh1, BH0, acc10); acc10 = MFMA(wh1, BL0, acc10); acc10 = MFMA(wl1, BH0, acc10); \
    acc11 = MFMA(wh1, BH1, acc11); acc11 = MFMA(wh1, BL1, acc11); acc11 = MFMA(wl1, BH1, acc11); }

#define COMPUTE(BUF) { \
    const char* wb_ = smem + ((BUF) << 15); \
    KKSTEP(0, bh00, bl00, bh10, bl10) \
    KKSTEP(1, bh01, bl01, bh11, bl11) \
    KKSTEP(2, bh02, bl02, bh12, bl12) \
    KKSTEP(3, bh03, bl03, bh13, bl13) }

// acc = 2^20 * conv -> unscale exactly, + bias, relu
#define EPI(ACC, MI, NI) { \
    const int coB_ = co0 + (wm << 6) + ((MI) << 5) + hl4; \
    const int pt_  = p0 + (wn << 6) + ((NI) << 5) + l31; \
    _Pragma("unroll") \
    for (int g_ = 0; g_ < 4; ++g_) { \
        _Pragma("unroll") \
        for (int q_ = 0; q_ < 4; ++q_) { \
            const int co_ = coB_ + (g_ << 3) + q_; \
            const float v_ = ACC[g_ * 4 + q_] * 9.5367431640625e-07f + bconv[co_]; \
            x[((size_t)((b << 9) + co_) << 13) + pt_] = fmaxf(v_, 0.f); \
        } } }

__global__ __launch_bounds__(256, 2) void k_conv(const float* __restrict__ in,
                                                 const u16* __restrict__ Wg,
                                                 const float* __restrict__ bconv,
                                                 float* __restrict__ x) {
    __shared__ __align__(16) char smem[65536];   // W double-buffer: 2 x 32 KB
    const int tid  = threadIdx.x;
    const int bx   = blockIdx.x;        // 64 spatial tiles (128 pts each)
    const int nt   = blockIdx.y;        // 4 cout tiles of 128
    const int b    = blockIdx.z;
    const int p0   = bx << 7;
    const int d0   = bx >> 3;
    const int h0   = (bx & 7) << 2;
    const int co0  = nt << 7;

    const int lane = tid & 63;
    const int wv   = tid >> 6;          // wave id
    const int wm   = wv & 1;            // cout 64-half
    const int wn   = wv >> 1;           // pt 64-half
    const int l31  = lane & 31;         // frag row/col
    const int cq   = lane >> 5;         // frag k-octet half
    const int hl4  = cq << 2;           // C/D row group
    const int rsw  = l31 & 15;          // W-row XOR swizzle key
    const int rm0  = (wm << 6) + l31;   // weight LDS rows (256 B each)
    const int rm1  = rm0 + 32;
    const int ln16 = lane << 4;

    const int t0   = (d0 == 0) ? 9 : 0;
    const int nTap = 27 - (((d0 == 0) || (d0 == 7)) ? 9 : 0);
    const int NS   = nTap * 2;          // stages: tap x 2 ci-halves of 64

    const char* WgB = (const char*)Wg;

    float y[2][4][8];                   // act prefetch (constant-indexed -> VGPRs)
    f16x8 bh00, bh01, bh02, bh03, bh10, bh11, bh12, bh13;
    f16x8 bl00, bl01, bl02, bl03, bl10, bl11, bl12, bl13;
    f32x16 acc00 = Z16, acc01 = Z16, acc10 = Z16, acc11 = Z16;

    WISSUE(0, 0)
    ALOADISS(0)                         // prologue act loads for stage 0
    __syncthreads();                    // drains W staging (and act loads)

    for (int s = 0; s < NS; ++s) {
        if (s + 1 < NS) { WISSUE(s + 1, (s + 1) & 1) }   // async W -> alt buf
        CVTALL()                        // y(s) -> frags (reads prev-stage loads)
        __builtin_amdgcn_sched_barrier(0);
        if (s + 1 < NS) { ALOADISS(s + 1) }   // issue next acts; in flight below
        __builtin_amdgcn_sched_barrier(0);
        COMPUTE(s & 1)                  // 16 ds_read_b128 + 48 MFMA cover latency
        __syncthreads();                // vmcnt-drain + barrier once per stage
    }

    EPI(acc00, 0, 0)
    EPI(acc01, 0, 1)
    EPI(acc10, 1, 0)
    EPI(acc11, 1, 1)
}

// ---------------- heads GEMM + score/box epilogue + fused score histogram ----------------
// R12 form (measured best): unchanged.
__global__ __launch_bounds__(256) void k_heads(const float* __restrict__ x,
                                               const float* __restrict__ Wht,
                                               const float* __restrict__ bcls,
                                               const float* __restrict__ bbb,
                                               const float* __restrict__ iminfo,
                                               float* __restrict__ scores,
                                               float* __restrict__ boxes,
                                               unsigned int* __restrict__ hist) {
    __shared__ __align__(16) float smx[4096];    // x chunk [ch32][pt128]  16 KB
    __shared__ __align__(16) float Whs[2560];    // weight chunk [kk32][80] 10 KB
    __shared__ __align__(16) float ex[10240];    // exchange [pt128][80]    40 KB
    const int tid = threadIdx.x;
    const int p0  = blockIdx.x * 128;
    const int b   = blockIdx.y;
    const int pl  = tid & 31;     // 32 point-lanes, 4 consecutive points each
    const int og  = tid >> 5;     // 8 output groups of 9

    float acc[4][9] = {};

    for (int cc = 0; cc < 512; cc += 32) {
        __syncthreads();
        #pragma unroll
        for (int i = 0; i < 4; ++i) {
            int e4 = tid + i * 256;          // 1024 float4s
            int ch = e4 >> 5;
            int pt4 = (e4 & 31) * 4;
            *(float4*)&smx[ch * 128 + pt4] =
                *(const float4*)&x[((size_t)(b * COUT + cc + ch) << 13) + p0 + pt4];
        }
        #pragma unroll
        for (int i = 0; i < 10; ++i) {
            int e = tid + i * 256;
            Whs[e] = Wht[cc * 80 + e];
        }
        __syncthreads();
        for (int kk = 0; kk < 32; ++kk) {
            float4 a4 = *(const float4*)&smx[kk * 128 + pl * 4];
            const float* wp = &Whs[kk * 80 + og * 10];
            float2 w0 = *(const float2*)(wp);
            float2 w1 = *(const float2*)(wp + 2);
            float2 w2 = *(const float2*)(wp + 4);
            float2 w3 = *(const float2*)(wp + 6);
            float  w8 = wp[8];
            float wv[9] = {w0.x, w0.y, w1.x, w1.y, w2.x, w2.y, w3.x, w3.y, w8};
            #pragma unroll
            for (int k = 0; k < 9; ++k) {
                float wk = wv[k];
                acc[0][k] += a4.x * wk;
                acc[1][k] += a4.y * wk;
                acc[2][k] += a4.z * wk;
                acc[3][k] += a4.w * wk;
            }
        }
    }

    __syncthreads();
    #pragma unroll
    for (int pi = 0; pi < 4; ++pi)
        #pragma unroll
        for (int k = 0; k < 9; ++k)
            ex[(pl * 4 + pi) * 80 + og * 10 + k] = acc[pi][k];
    __syncthreads();

    if (tid < 128) {
        const int p = p0 + tid;
        float v[72];
        #pragma unroll
        for (int og2 = 0; og2 < 8; ++og2)
            #pragma unroll
            for (int k = 0; k < 9; ++k)
                v[og2 * 9 + k] = ex[tid * 80 + og2 * 10 + k];

        const float im0 = iminfo[b * 3 + 0], im1 = iminfo[b * 3 + 1], im2 = iminfo[b * 3 + 2];
        const float hix = im2 - 1.f, hiy = im1 - 1.f, hiz = im0 - 1.f;
        const int d = p >> 10, h = (p >> 5) & 31, w = p & 31;
        const float sx = w * 8.f, sy = h * 8.f, sz = d * 8.f;

        #pragma unroll 1
        for (int a = 0; a < 9; ++a) {
            float c0 = v[a] + bcls[a];
            float c1 = v[9 + a] + bcls[9 + a];
            float m  = fmaxf(c0, c1);
            float e0 = expf(c0 - m), e1 = expf(c1 - m);
            float sc = e1 / (e0 + e1);
            scores[b * NANCH + p * 9 + a] = sc;
            atomicAdd(&hist[b * 65536 + (__float_as_uint(sc) >> 16)], 1u);

            float aw = (float)(32 << (a % 3));                 // x,y size = 8*SCALES
            float ad = aw * 0.5f * (float)(1 << (a / 3));      // z size = aw*RATIOS
            float ax1 = sx + 3.5f - 0.5f * (aw - 1.f);
            float ax2 = sx + 3.5f + 0.5f * (aw - 1.f);
            float ay1 = sy + 3.5f - 0.5f * (aw - 1.f);
            float ay2 = sy + 3.5f + 0.5f * (aw - 1.f);
            float az1 = sz + 3.5f - 0.5f * (ad - 1.f);
            float az2 = sz + 3.5f + 0.5f * (ad - 1.f);
            float ww_ = ax2 - ax1 + 1.f, hh_ = ay2 - ay1 + 1.f, dd_ = az2 - az1 + 1.f;
            float cx = ax1 + 0.5f * ww_, cy = ay1 + 0.5f * hh_, cz = az1 + 0.5f * dd_;

            const float* dv = &v[18 + a * 6];
            float dx = dv[0] + bbb[a * 6 + 0];
            float dy = dv[1] + bbb[a * 6 + 1];
            float dz = dv[2] + bbb[a * 6 + 2];
            float dw = dv[3] + bbb[a * 6 + 3];
            float dh = dv[4] + bbb[a * 6 + 4];
            float dd2 = dv[5] + bbb[a * 6 + 5];
            float pcx = dx * ww_ + cx, pcy = dy * hh_ + cy, pcz = dz * dd_ + cz;
            float pw = expf(dw) * ww_, ph = expf(dh) * hh_, pd = expf(dd2) * dd_;
            float x1 = fminf(fmaxf(pcx - 0.5f * pw, 0.f), hix);
            float y1 = fminf(fmaxf(pcy - 0.5f * ph, 0.f), hiy);
            float z1 = fminf(fmaxf(pcz - 0.5f * pd, 0.f), hiz);
            float x2 = fminf(fmaxf(pcx + 0.5f * pw, 0.f), hix);
            float y2 = fminf(fmaxf(pcy + 0.5f * ph, 0.f), hiy);
            float z2 = fminf(fmaxf(pcz + 0.5f * pd, 0.f), hiz);
            float* bp = &boxes[(size_t)(b * NANCH + p * 9 + a) * 6];
            bp[0] = x1; bp[1] = y1; bp[2] = z1; bp[3] = x2; bp[4] = y2; bp[5] = z2;
        }
    }
}

// ---------------- fused cutoff + compact (one block per batch) ----------------
__global__ __launch_bounds__(1024) void k_cutcompact(const float* __restrict__ scores,
                                                     const unsigned int* __restrict__ hist,
                                                     unsigned long long* __restrict__ cand) {
    __shared__ unsigned int cs[1024], scan[1024];
    __shared__ unsigned int sh_cut, sh_pos;
    const int b = blockIdx.x, tid = threadIdx.x;
    const unsigned int* h = hist + b * 65536;
    unsigned int s = 0;
    for (int i = 0; i < 64; ++i) s += h[tid * 64 + i];
    cs[tid] = s; scan[tid] = s;
    if (tid == 0) sh_pos = 0;
    __syncthreads();
    for (int d = 1; d < 1024; d <<= 1) {           // scan[c] -> sum_{c'>=c} cs[c']
        unsigned int v = scan[tid];
        unsigned int add = (tid + d < 1024) ? scan[tid + d] : 0u;
        __syncthreads();
        scan[tid] = v + add;
        __syncthreads();
    }
    unsigned int above = (tid + 1 < 1024) ? scan[tid + 1] : 0u;   // strictly above this chunk
    if (above < PRE && above + cs[tid] >= PRE) {   // exactly one thread
        unsigned int cum = above;
        for (int x = tid * 64 + 63; x >= tid * 64; --x) {
            cum += h[x];
            if (cum >= PRE) { sh_cut = (unsigned int)x; break; }
        }
    }
    __syncthreads();
    const unsigned int cut = sh_cut;
    const float* sc = scores + b * NANCH;
    for (int i = tid; i < NANCH; i += 1024) {
        unsigned int u = __float_as_uint(sc[i]);
        if ((u >> 16) >= cut) {
            unsigned int pos = atomicAdd(&sh_pos, 1u);
            if (pos < CAP) cand[b * CAP + pos] = ((unsigned long long)(~u) << 32) | (unsigned)i;
        }
    }
    __syncthreads();
    const unsigned int cnt = (sh_pos < CAP) ? sh_pos : CAP;
    for (int i = (int)cnt + tid; i < CAP; i += 1024)
        cand[b * CAP + i] = ~0ull;
}

// bitonic sort CAP keys asc (key = ~score_bits || idx => score desc, idx asc);
// first 2048 are the sorted top-2048; gather their boxes.
__global__ __launch_bounds__(1024) void k_sort2(const unsigned long long* __restrict__ cand,
                                                const float* __restrict__ boxes,
                                                float* __restrict__ sboxes) {
    __shared__ unsigned long long sk[CAP];
    const int b = blockIdx.x, tid = threadIdx.x;
    for (int i = tid; i < CAP; i += 1024) sk[i] = cand[b * CAP + i];
    __syncthreads();
    for (int k = 2; k <= CAP; k <<= 1) {
        for (int j = k >> 1; j > 0; j >>= 1) {
            #pragma unroll 1
            for (int i = tid; i < CAP; i += 1024) {
                int ixj = i ^ j;
                if (ixj > i) {
                    unsigned long long va = sk[i], vb = sk[ixj];
                    bool up = ((i & k) == 0);
                    if ((va > vb) == up) { sk[i] = vb; sk[ixj] = va; }
                }
            }
            __syncthreads();
        }
    }
    for (int r = tid; r < PRE; r += 1024) {
        unsigned int n = (unsigned int)(sk[r] & 0xFFFFFFFFull);
        const float* src = &boxes[(size_t)(b * NANCH + (int)n) * 6];
        float* dst = &sboxes[(size_t)(b * PRE + r) * 6];
        #pragma unroll
        for (int c = 0; c < 6; ++c) dst[c] = src[c];
    }
}

// suppression bitmask (upper triangle only): mask[b][i][w] bit j <=> j>i && IoU>0.7
__global__ __launch_bounds__(256) void k_mask(const float* __restrict__ sboxes,
                                              unsigned long long* __restrict__ mask) {
    if (blockIdx.y < blockIdx.x) return;   // j0 < i0: never read (k_nms gates by word)
    __shared__ float rb[64 * 6], cb[64 * 6];
    const int i0 = blockIdx.x * 64, j0 = blockIdx.y * 64, b = blockIdx.z;
    const int tid = threadIdx.x;
    for (int e = tid; e < 384; e += 256) {
        rb[e] = sboxes[(size_t)(b * PRE + i0) * 6 + e];
        cb[e] = sboxes[(size_t)(b * PRE + j0) * 6 + e];
    }
    __syncthreads();
    const int wave = tid >> 6, lane = tid & 63;
    const float bx1 = cb[lane * 6 + 0], by1 = cb[lane * 6 + 1], bz1 = cb[lane * 6 + 2];
    const float bx2 = cb[lane * 6 + 3], by2 = cb[lane * 6 + 4], bz2 = cb[lane * 6 + 5];
    const float vb = (bx2 - bx1 + 1.f) * (by2 - by1 + 1.f) * (bz2 - bz1 + 1.f);
    const int j = j0 + lane;
    for (int rr = 0; rr < 16; ++rr) {
        const int il = wave * 16 + rr;
        const int i = i0 + il;
        float ax1 = rb[il * 6 + 0], ay1 = rb[il * 6 + 1], az1 = rb[il * 6 + 2];
        float ax2 = rb[il * 6 + 3], ay2 = rb[il * 6 + 4], az2 = rb[il * 6 + 5];
        float va = (ax2 - ax1 + 1.f) * (ay2 - ay1 + 1.f) * (az2 - az1 + 1.f);
        float ix = fmaxf(fminf(ax2, bx2) - fmaxf(ax1, bx1) + 1.f, 0.f);
        float iy = fmaxf(fminf(ay2, by2) - fmaxf(ay1, by1) + 1.f, 0.f);
        float iz = fmaxf(fminf(az2, bz2) - fmaxf(az1, bz1) + 1.f, 0.f);
        float inter = ix * iy * iz;
        float iou = inter / (va + vb - inter);
        bool bit = (j > i) && (iou > NMS_TH);
        unsigned long long word = __ballot(bit);
        if (lane == 0) mask[(size_t)(b * PRE + i) * 32 + (j0 >> 6)] = word;
    }
}

// single-wave greedy NMS scan + ROI output; 8-deep mask-row prefetch.
__global__ __launch_bounds__(64) void k_nms(const unsigned long long* __restrict__ mask,
                                            const float* __restrict__ sboxes,
                                            float* __restrict__ out) {
    const int b = blockIdx.x, lane = threadIdx.x;
    __shared__ int sel[POST];
    unsigned long long keep = ~0ull;          // lane l<32 owns bits [64l,64l+64)
    const int lw = lane & 31;
    const unsigned long long* mrow = mask + (size_t)b * PRE * 32 + lw;
    unsigned long long b0 = mrow[0 * 32], b1 = mrow[1 * 32], b2 = mrow[2 * 32], b3 = mrow[3 * 32];
    unsigned long long b4 = mrow[4 * 32], b5 = mrow[5 * 32], b6 = mrow[6 * 32], b7 = mrow[7 * 32];
    int kcount = 0;

#define NMS_STEP(J, BUF)                                                        \
    {                                                                           \
        int i = i0 + (J);                                                       \
        unsigned long long cur = (lw >= (i >> 6)) ? BUF : 0ull;                 \
        int nr = i0 + 8 + (J);                                                  \
        BUF = (nr < PRE) ? mrow[(size_t)nr * 32] : 0ull;                        \
        unsigned long long kw = __shfl(keep, i >> 6);                           \
        if ((kw >> (i & 63)) & 1ull) {                                          \
            if (lane < 32) keep &= ~cur;                                        \
            if (lane == 0 && kcount < POST) sel[kcount] = i;                    \
            ++kcount;                                                           \
            if (kcount >= POST) goto nms_done;                                  \
        }                                                                       \
    }

    for (int i0 = 0; i0 < PRE; i0 += 8) {
        NMS_STEP(0, b0) NMS_STEP(1, b1) NMS_STEP(2, b2) NMS_STEP(3, b3)
        NMS_STEP(4, b4) NMS_STEP(5, b5) NMS_STEP(6, b6) NMS_STEP(7, b7)
    }
nms_done:
    __syncthreads();
    const int kc = kcount;
    for (int r = lane; r < POST; r += 64) {
        float* op = &out[(size_t)(b * POST + r) * 7];
        op[0] = (float)b;
        if (r < kc) {
            const float* sb = &sboxes[(size_t)(b * PRE + sel[r]) * 6];
            #pragma unroll
            for (int c = 0; c < 6; ++c) op[1 + c] = sb[c];
        } else {
            #pragma unroll
            for (int c = 0; c < 6; ++c) op[1 + c] = 0.f;
        }
    }
#undef NMS_STEP
}

extern "C" void kernel_launch(void* const* d_in, const int* in_sizes, int n_in,
                              void* d_out, int out_size, void* d_ws, size_t ws_size,
                              hipStream_t stream) {
    const float* base_feat = (const float*)d_in[0];
    const float* im_info   = (const float*)d_in[1];
    const float* W_conv    = (const float*)d_in[4];
    const float* b_conv    = (const float*)d_in[5];
    const float* W_cls     = (const float*)d_in[6];
    const float* b_cls     = (const float*)d_in[7];
    const float* W_bbox    = (const float*)d_in[8];
    const float* b_bbox    = (const float*)d_in[9];

    char* ws = (char*)d_ws;
    u16* Wg        = (u16*)(ws + OFF_WT);
    float* Wht     = (float*)(ws + OFF_WHT);
    float* x       = (float*)(ws + OFF_X);
    float* scores  = (float*)(ws + OFF_SC);
    float* boxes   = (float*)(ws + OFF_BX);
    float* sboxes  = (float*)(ws + OFF_SB);
    unsigned long long* mask = (unsigned long long*)(ws + OFF_MK);
    unsigned int* hist = (unsigned int*)(ws + OFF_HIST);
    unsigned long long* cand = (unsigned long long*)(ws + OFF_CAND);

    const int NTRANS = NT_WT + NT_WHT;
    k_wtrans<<<(NTRANS + 255) / 256, 256, 0, stream>>>(W_conv, Wg, W_cls, W_bbox, Wht);
    k_conv<<<dim3(64, 4, 2), 256, 0, stream>>>(base_feat, Wg, b_conv, x);
    // Wg region dead now; zero hist (aliases Wg) AFTER k_conv, before k_heads.
    hipMemsetAsync(hist, 0, BATCH * 65536 * sizeof(unsigned int), stream);
    k_heads<<<dim3(64, 2), 256, 0, stream>>>(x, Wht, b_cls, b_bbox, im_info, scores, boxes, hist);
    k_cutcompact<<<BATCH, 1024, 0, stream>>>(scores, hist, cand);
    k_sort2<<<BATCH, 1024, 0, stream>>>(cand, boxes, sboxes);
    k_mask<<<dim3(32, 32, 2), 256, 0, stream>>>(sboxes, mask);
    k_nms<<<BATCH, 64, 0, stream>>>(mask, sboxes, (float*)d_out);
}